// Round 17
// baseline (548.650 us; speedup 1.0000x reference)
//
#include <hip/hip_runtime.h>
#include <hip/hip_bf16.h>

static constexpr float NEG_SLOPE = 0.2f;
static constexpr float LN_EPS = 1e-5f;

typedef float v2f __attribute__((ext_vector_type(2)));
typedef __attribute__((ext_vector_type(8))) short bf16x8;
typedef __attribute__((ext_vector_type(4))) float f32x4;

// f32 -> bf16 (RNE) as ushort
__device__ __forceinline__ unsigned f2b(float f) {
  unsigned u = __float_as_uint(f);
  return (u + 0x7fffu + ((u >> 16) & 1u)) >> 16;
}
__device__ __forceinline__ v2f b2f2(ushort2 u) {
  v2f r;
  r.x = __uint_as_float((unsigned)u.x << 16);
  r.y = __uint_as_float((unsigned)u.y << 16);
  return r;
}

// ---- 16-lane (head-group) sum via DPP ----
__device__ __forceinline__ float head_sum16(float x) {
  float t;
  t = __int_as_float(__builtin_amdgcn_update_dpp(
      0, __float_as_int(x), 0xB1, 0xF, 0xF, true));  // quad_perm [1,0,3,2]
  x += t;
  t = __int_as_float(__builtin_amdgcn_update_dpp(
      0, __float_as_int(x), 0x4E, 0xF, 0xF, true));  // quad_perm [2,3,0,1]
  x += t;
  t = __int_as_float(__builtin_amdgcn_update_dpp(
      0, __float_as_int(x), 0x124, 0xF, 0xF, true));  // row_ror:4
  x += t;
  t = __int_as_float(__builtin_amdgcn_update_dpp(
      0, __float_as_int(x), 0x128, 0xF, 0xF, true));  // row_ror:8
  x += t;
  return x;
}

// ---- K0: pack Wl|Wr into MFMA B-fragment order (bf16) + bias concat ----
// Also zeroes deg/cursor, the alloc counter, LN-stat accums.
__global__ __launch_bounds__(256) void k_packB(
    const float* __restrict__ Wl, const float* __restrict__ Wr,
    const float* __restrict__ bl, const float* __restrict__ br,
    ushort* __restrict__ Bpack, float* __restrict__ bcat,
    int* __restrict__ degcur, int N2, int* __restrict__ tot,
    double* __restrict__ red)
{
  int tid = blockIdx.x * 256 + threadIdx.x;  // 0..4095
  int l = tid & 63, s = (tid >> 6) & 3, t = tid >> 8;
  int col = t * 16 + (l & 15);
  int kb = s * 32 + (l >> 4) * 8;
  const float* __restrict__ W = (col < 128) ? Wl : Wr;
  int c = col & 127;
  unsigned p[4];
#pragma unroll
  for (int i = 0; i < 4; ++i) {
    unsigned lo = f2b(W[(size_t)(kb + 2 * i) * 128 + c]);
    unsigned hi = f2b(W[(size_t)(kb + 2 * i + 1) * 128 + c]);
    p[i] = lo | (hi << 16);
  }
  *(uint4*)(Bpack + (size_t)tid * 8) = make_uint4(p[0], p[1], p[2], p[3]);
  if (tid < 256) bcat[tid] = (tid < 128) ? bl[tid] : br[tid - 128];
  if (tid < 2) red[tid] = 0.0;
  if (tid == 0) *tot = 0;
  for (int i = tid; i < N2; i += 4096) degcur[i] = 0;  // deg + cursor
}

// ---- K1: xl (bf16) | xr (f32, into outz) = x @ (Wl|Wr) + b via bf16 MFMA ----
__global__ __launch_bounds__(256) void k_gemm_mfma(
    const float* __restrict__ x, const ushort* __restrict__ Bpack,
    const float* __restrict__ bcat, ushort* __restrict__ xl,
    float* __restrict__ outz, int n, const int* __restrict__ dst,
    int* __restrict__ deg, int E)
{
  const int lane = threadIdx.x & 63;
  const int w = threadIdx.x >> 6;
  const int row0 = blockIdx.x * 64 + w * 16;
  const int rowA = min(row0 + (lane & 15), n - 1);
  const int kgrp = lane >> 4;

  f32x4 acc[16];
#pragma unroll
  for (int t = 0; t < 16; ++t) acc[t] = (f32x4){0.f, 0.f, 0.f, 0.f};

#pragma unroll
  for (int s = 0; s < 4; ++s) {
    const float4* ap =
        (const float4*)(x + (size_t)rowA * 128 + s * 32 + kgrp * 8);
    float4 a0 = ap[0], a1 = ap[1];
    bf16x8 a;
    a[0] = (short)f2b(a0.x); a[1] = (short)f2b(a0.y);
    a[2] = (short)f2b(a0.z); a[3] = (short)f2b(a0.w);
    a[4] = (short)f2b(a1.x); a[5] = (short)f2b(a1.y);
    a[6] = (short)f2b(a1.z); a[7] = (short)f2b(a1.w);
#pragma unroll
    for (int t = 0; t < 16; ++t) {
      bf16x8 b =
          *(const bf16x8*)(Bpack + (((size_t)t * 4 + s) * 64 + lane) * 8);
      acc[t] = __builtin_amdgcn_mfma_f32_16x16x32_bf16(a, b, acc[t], 0, 0, 0);
    }
  }

  const int colg = lane & 15;
  const int rbase = row0 + (lane >> 4) * 4;
#pragma unroll
  for (int t = 0; t < 16; ++t) {
    const int col = t * 16 + colg;
    const float bia = bcat[col];
    if (col < 128) {
#pragma unroll
      for (int r = 0; r < 4; ++r) {
        const int R = rbase + r;
        if (R < n) xl[(size_t)R * 128 + col] = (ushort)f2b(acc[t][r] + bia);
      }
    } else {
      const int c = col - 128;
#pragma unroll
      for (int r = 0; r < 4; ++r) {
        const int R = rbase + r;
        if (R < n) outz[(size_t)R * 128 + c] = acc[t][r] + bia;
      }
    }
  }

  // folded: in-degree histogram
  for (int e = blockIdx.x * 256 + threadIdx.x; e < E; e += gridDim.x * 256)
    atomicAdd(&deg[dst[e]], 1);
}

// ---- K2: allocate CSR segments, PADDED to multiples of 16 slots ----
__global__ __launch_bounds__(256) void k_allocscan(
    const int* __restrict__ deg, int* __restrict__ offs, int* __restrict__ tot,
    int n)
{
  __shared__ int s[256];
  __shared__ int base;
  const int b = blockIdx.x, t = threadIdx.x, i = b * 256 + t;
  const int v = (i < n) ? ((deg[i] + 15) & ~15) : 0;
  s[t] = v;
  __syncthreads();
  for (int o = 1; o < 256; o <<= 1) {
    int u = (t >= o) ? s[t - o] : 0;
    __syncthreads();
    s[t] += u;
    __syncthreads();
  }
  if (t == 255) base = atomicAdd(tot, s[255]);
  __syncthreads();
  if (i < n) offs[i] = base + s[t] - v;
}

// ---- K3: fill CSR: src id + ea bf16 in MFMA-A-fragment chunk layout ----
// Chunk = 16 edges = 512B of csr_ea. Edge at slot pos: chunk=pos>>4, r=pos&15;
// k0..7 -> uint4 at chunk*32 + r; k8..15 -> uint4 at chunk*32 + r + 16.
__global__ __launch_bounds__(256) void k_fill(
    const int* __restrict__ src, const int* __restrict__ dst,
    const int* __restrict__ offs, int* __restrict__ cursor,
    const float4* __restrict__ ea4, int* __restrict__ csr_src,
    uint4* __restrict__ csr_ea4, int E)
{
  int e = blockIdx.x * 256 + threadIdx.x;
  if (e >= E) return;
  int d = dst[e];
  int pos = offs[d] + atomicAdd(&cursor[d], 1);
  csr_src[pos] = src[e];
  float4 r0 = ea4[(size_t)e * 4 + 0], r1 = ea4[(size_t)e * 4 + 1];
  float4 r2 = ea4[(size_t)e * 4 + 2], r3 = ea4[(size_t)e * 4 + 3];
  const int chunk = pos >> 4, r = pos & 15;
  csr_ea4[(size_t)chunk * 32 + r] =
      make_uint4(f2b(r0.x) | (f2b(r0.y) << 16), f2b(r0.z) | (f2b(r0.w) << 16),
                 f2b(r1.x) | (f2b(r1.y) << 16), f2b(r1.z) | (f2b(r1.w) << 16));
  csr_ea4[(size_t)chunk * 32 + r + 16] =
      make_uint4(f2b(r2.x) | (f2b(r2.y) << 16), f2b(r2.z) | (f2b(r2.w) << 16),
                 f2b(r3.x) | (f2b(r3.y) << 16), f2b(r3.z) | (f2b(r3.w) << 16));
}

// ---- K4: fused: MFMA emb (16-edge chunks) + softmax + agg + z + LN stats ----
// One wave per node; lane j owns channels {2j,2j+1}; head = j>>4.
// Per chunk: A = 16 edges x 16 ea (bf16, K zero-padded to 32), B = We
// fragments (8 n-tiles) -> 8 MFMA -> emb to per-wave LDS -> ds_read_b64/edge.
// Self-loop emb via linearity: embsum/len. No running max. xr from outz.
__global__ __launch_bounds__(256) void k_fused(
    const int* __restrict__ csr_src, const ushort* __restrict__ csr_ea,
    const int* __restrict__ offs, const int* __restrict__ deg,
    const ushort* __restrict__ xl, const float* __restrict__ We,
    const float* __restrict__ att, const float* __restrict__ x,
    const float* __restrict__ bias, float* __restrict__ outz,
    double* __restrict__ red, int N)
{
  const int lane = threadIdx.x & 63;
  const int wv = threadIdx.x >> 6;
  const int gw = __builtin_amdgcn_readfirstlane(blockIdx.x * 4 + wv);
  const int nw = gridDim.x * 4;
  const v2f* __restrict__ X2 = (const v2f*)x;
  v2f* __restrict__ Z2 = (v2f*)outz;

  __shared__ float sEmb[4][16 * 128];  // 8KB per wave
  float* const myEmb = sEmb[wv];

  // B fragments of We (zero-padded K=32): weB[t], col = t*16+(lane&15),
  // k = (lane>>4)*8 + i (real for k<16, else 0)
  bf16x8 weB[8];
  {
    const int colb = lane & 15;
    const int k0 = (lane >> 4) * 8;
#pragma unroll
    for (int t = 0; t < 8; ++t) {
      bf16x8 b;
#pragma unroll
      for (int i = 0; i < 8; ++i) {
        const int k = k0 + i;
        b[i] = (k < 16) ? (short)f2b(We[(size_t)k * 128 + t * 16 + colb])
                        : (short)0;
      }
      weB[t] = b;
    }
  }
  const v2f a2 = ((const v2f*)att)[lane];
  const v2f b2 = ((const v2f*)bias)[lane];

  float sred = 0.f, s2red = 0.f;

  int node = gw;
  int beg = 0, len = 0;
  if (node < N) {
    beg = offs[node];
    len = deg[node];
  }
  uint4 afrag = {0, 0, 0, 0};
  if (node < N && len > 0 && lane < 32)
    afrag = *(const uint4*)(csr_ea + ((size_t)(beg >> 4) * 32 + lane) * 8);

  while (node < N) {
    const int nodeN = node + nw;
    int begN = 0, lenN = 0;
    if (nodeN < N) {
      begN = offs[nodeN];
      lenN = deg[nodeN];
    }

    const v2f xrv = Z2[(size_t)node * 64 + lane];  // xr row (f32)
    const v2f xvSelf =
        b2f2(*(const ushort2*)(xl + (size_t)node * 128 + 2 * lane));

    float den = 0.f;
    v2f acc = {0.f, 0.f}, embsum = {0.f, 0.f};
    const int nchunk = (len + 15) >> 4;
    const int c0 = beg >> 4;

    // xv pipeline (2-ahead): xv0 (cur), xv1 (next), s2 (next-next src)
    int g = beg;
    v2f xv0 = {0.f, 0.f}, xv1 = {0.f, 0.f};
    int s2 = 0;
    if (len > 0) {
      const int sa = csr_src[beg];
      xv0 = b2f2(*(const ushort2*)(xl + (size_t)sa * 128 + 2 * lane));
      const int sb = csr_src[beg + 1];  // pads zeroed, safe
      xv1 = b2f2(*(const ushort2*)(xl + (size_t)sb * 128 + 2 * lane));
      s2 = csr_src[beg + 2];
    }

    for (int c = 0; c < nchunk; ++c) {
      uint4 afragN = {0, 0, 0, 0};
      if (lane < 32) {
        if (c + 1 < nchunk)
          afragN =
              *(const uint4*)(csr_ea + ((size_t)(c0 + c + 1) * 32 + lane) * 8);
        else if (lenN > 0)
          afragN =
              *(const uint4*)(csr_ea + ((size_t)(begN >> 4) * 32 + lane) * 8);
      }
      // 8 MFMA -> per-wave LDS emb buffer
      {
        const int colb = lane & 15;
        const int row4 = (lane >> 4) * 4;
        const bf16x8 a = *(const bf16x8*)&afrag;
#pragma unroll
        for (int t = 0; t < 8; ++t) {
          f32x4 cf = __builtin_amdgcn_mfma_f32_16x16x32_bf16(
              a, weB[t], (f32x4){0.f, 0.f, 0.f, 0.f}, 0, 0, 0);
#pragma unroll
          for (int q = 0; q < 4; ++q)
            myEmb[(row4 + q) * 128 + t * 16 + colb] = cf[q];
        }
      }
      const int m = min(16, len - c * 16);
      for (int i = 0; i < m; ++i) {
        const v2f emb = *(const v2f*)(myEmb + i * 128 + 2 * lane);
        const v2f xv2 =
            b2f2(*(const ushort2*)(xl + (size_t)s2 * 128 + 2 * lane));
        const int s3 = csr_src[g + 3];  // pads zeroed, safe
        embsum += emb;
        v2f mm = (xv0 + emb) + xrv;
        v2f ml;
        ml.x = fmaxf(mm.x, NEG_SLOPE * mm.x);
        ml.y = fmaxf(mm.y, NEG_SLOPE * mm.y);
        const float part = head_sum16(fmaf(ml.y, a2.y, ml.x * a2.x));
        const float p = __expf(part);
        den += p;
        acc += xv0 * p;
        xv0 = xv1;
        xv1 = xv2;
        s2 = s3;
        ++g;
      }
      afrag = afragN;
    }
    if (nchunk == 0 && lenN > 0 && lane < 32)  // isolated node: prefetch next
      afrag = *(const uint4*)(csr_ea + ((size_t)(begN >> 4) * 32 + lane) * 8);

    // self loop: emb = embsum/len (linearity of emb in ea); 0 if isolated
    {
      const float inv = (len > 0) ? 1.f / (float)len : 0.f;
      const v2f embS = embsum * inv;
      v2f mm = (xvSelf + embS) + xrv;
      v2f ml;
      ml.x = fmaxf(mm.x, NEG_SLOPE * mm.x);
      ml.y = fmaxf(mm.y, NEG_SLOPE * mm.y);
      const float part = head_sum16(fmaf(ml.y, a2.y, ml.x * a2.x));
      const float p = __expf(part);
      den += p;
      acc += xvSelf * p;
    }

    const float invden = 1.f / den;
    const float o0 = acc.x * invden;
    const float o1 = acc.y * invden;

    // z = x + attn + bias (overwrites xr row); LN stats on z
    const v2f xvn = X2[(size_t)node * 64 + lane];
    const float v0 = xvn.x + o0 + b2.x;
    const float v1 = xvn.y + o1 + b2.y;
    Z2[(size_t)node * 64 + lane] = (v2f){v0, v1};
    sred += v0 + v1;
    s2red += v0 * v0 + v1 * v1;

    node = nodeN;
    beg = begN;
    len = lenN;
  }

#pragma unroll
  for (int o = 32; o > 0; o >>= 1) {
    sred += __shfl_down(sred, o);
    s2red += __shfl_down(s2red, o);
  }
  __shared__ double ls[4], ls2[4];
  if ((threadIdx.x & 63) == 0) {
    ls[wv] = (double)sred;
    ls2[wv] = (double)s2red;
  }
  __syncthreads();
  if (threadIdx.x == 0) {
    unsafeAtomicAdd(red, ls[0] + ls[1] + ls[2] + ls[3]);
    unsafeAtomicAdd(red + 1, ls2[0] + ls2[1] + ls2[2] + ls2[3]);
  }
}

// ---- K5: normalize z, scale/shift, relu (in place) ----
__global__ __launch_bounds__(256) void k_final(
    float* __restrict__ z, const double* __restrict__ red,
    const float* __restrict__ lnw, const float* __restrict__ lnb, int M4)
{
  int i = blockIdx.x * 256 + threadIdx.x;
  if (i >= M4) return;
  const double invM = 1.0 / ((double)M4 * 4.0);
  const double mu = red[0] * invM;
  const double var = red[1] * invM - mu * mu;
  const float sc = rsqrtf((float)var + LN_EPS);
  const float muf = (float)mu;
  const float4* W4 = (const float4*)lnw;
  const float4* L4 = (const float4*)lnb;
  float4* Z4 = (float4*)z;
  float4 zv = Z4[i], wv = W4[i & 31], lv = L4[i & 31];
  float4 o;
  o.x = fmaxf((zv.x - muf) * sc * wv.x + lv.x, 0.f);
  o.y = fmaxf((zv.y - muf) * sc * wv.y + lv.y, 0.f);
  o.z = fmaxf((zv.z - muf) * sc * wv.z + lv.z, 0.f);
  o.w = fmaxf((zv.w - muf) * sc * wv.w + lv.w, 0.f);
  Z4[i] = o;
}

extern "C" void kernel_launch(void* const* d_in, const int* in_sizes, int n_in,
                              void* d_out, int out_size, void* d_ws,
                              size_t ws_size, hipStream_t stream)
{
  const float* x = (const float*)d_in[0];
  const int* ei = (const int*)d_in[1];
  const float* edge_attr = (const float*)d_in[2];
  const float* Wl = (const float*)d_in[3];
  const float* bl = (const float*)d_in[4];
  const float* Wr = (const float*)d_in[5];
  const float* br = (const float*)d_in[6];
  const float* We = (const float*)d_in[7];
  const float* att = (const float*)d_in[8];
  const float* bias = (const float*)d_in[9];
  const float* lnw = (const float*)d_in[10];
  const float* lnb = (const float*)d_in[11];
  float* out = (float*)d_out;

  const int N = in_sizes[0] / 128;
  const int E = in_sizes[1] / 2;
  const int M = N * 128;
  const int* srcp = ei;
  const int* dstp = ei + E;
  const int nb = (N + 255) / 256;
  const size_t SLOTS = (size_t)E + 15 * (size_t)N + 16;  // padded-alloc cap

  // workspace (~139 MB): xl bf16 | ints | csr_src | csr_ea (A-frag chunks)
  ushort* xl = (ushort*)d_ws;                      // M ushort
  int* deg = (int*)(xl + (size_t)M);               // N
  int* cursor = deg + N;                           // N
  int* offs = cursor + N;                          // N
  int* tot = offs + N;                             // 1 (+pad)
  int* csr_src = tot + 8;                          // SLOTS + 8
  ushort* csr_ea =
      (ushort*)((((size_t)(csr_src + SLOTS + 8)) + 63) & ~(size_t)63);
  double* red = (double*)(
      (((size_t)(csr_ea + SLOTS * 16 + 64)) + 127) & ~(size_t)127);
  ushort* Bpack = (ushort*)(red + 8);              // 4096*8 ushort (64 KB)
  float* bcat = (float*)(Bpack + 4096 * 8);        // 256 floats

  hipMemsetAsync(csr_src, 0, (SLOTS + 8) * sizeof(int), stream);

  k_packB<<<16, 256, 0, stream>>>(Wl, Wr, bl, br, Bpack, bcat, deg, 2 * N,
                                  tot, red);
  k_gemm_mfma<<<(N + 63) / 64, 256, 0, stream>>>(x, Bpack, bcat, xl, out, N,
                                                 dstp, deg, E);
  k_allocscan<<<nb, 256, 0, stream>>>(deg, offs, tot, N);
  k_fill<<<(E + 255) / 256, 256, 0, stream>>>(srcp, dstp, offs, cursor,
                                              (const float4*)edge_attr,
                                              csr_src, (uint4*)csr_ea, E);
  k_fused<<<2048, 256, 0, stream>>>(csr_src, csr_ea, offs, deg, xl, We, att,
                                    x, bias, out, red, N);
  k_final<<<(M / 4 + 255) / 256, 256, 0, stream>>>(out, red, lnw, lnb, M / 4);
}

// Round 18
// 483.951 us; speedup vs baseline: 1.1337x; 1.1337x over previous
//
#include <hip/hip_runtime.h>
#include <hip/hip_bf16.h>

static constexpr float NEG_SLOPE = 0.2f;
static constexpr float LN_EPS = 1e-5f;

typedef float v2f __attribute__((ext_vector_type(2)));
typedef __attribute__((ext_vector_type(8))) short bf16x8;
typedef __attribute__((ext_vector_type(4))) float f32x4;

// f32 -> bf16 (RNE) as ushort
__device__ __forceinline__ unsigned f2b(float f) {
  unsigned u = __float_as_uint(f);
  return (u + 0x7fffu + ((u >> 16) & 1u)) >> 16;
}
__device__ __forceinline__ v2f b2f2(ushort2 u) {
  v2f r;
  r.x = __uint_as_float((unsigned)u.x << 16);
  r.y = __uint_as_float((unsigned)u.y << 16);
  return r;
}
// bf16-in-dword expansion (SALU when operand is uniform)
__device__ __forceinline__ float sbl(unsigned w) {
  return __uint_as_float(w << 16);
}
__device__ __forceinline__ float sbh(unsigned w) {
  return __uint_as_float(w & 0xFFFF0000u);
}

// ---- 16-lane (head-group) sum via DPP ----
__device__ __forceinline__ float head_sum16(float x) {
  float t;
  t = __int_as_float(__builtin_amdgcn_update_dpp(
      0, __float_as_int(x), 0xB1, 0xF, 0xF, true));  // quad_perm [1,0,3,2]
  x += t;
  t = __int_as_float(__builtin_amdgcn_update_dpp(
      0, __float_as_int(x), 0x4E, 0xF, 0xF, true));  // quad_perm [2,3,0,1]
  x += t;
  t = __int_as_float(__builtin_amdgcn_update_dpp(
      0, __float_as_int(x), 0x124, 0xF, 0xF, true));  // row_ror:4
  x += t;
  t = __int_as_float(__builtin_amdgcn_update_dpp(
      0, __float_as_int(x), 0x128, 0xF, 0xF, true));  // row_ror:8
  x += t;
  return x;
}

// ---- K0: pack Wl|Wr into MFMA B-fragment order (bf16) + bias concat ----
// Also zeroes deg/cursor, the alloc counter, csr_src pad, LN-stat accums.
__global__ __launch_bounds__(256) void k_packB(
    const float* __restrict__ Wl, const float* __restrict__ Wr,
    const float* __restrict__ bl, const float* __restrict__ br,
    ushort* __restrict__ Bpack, float* __restrict__ bcat,
    int* __restrict__ degcur, int N2, int* __restrict__ tot,
    int* __restrict__ src_pad, double* __restrict__ red)
{
  int tid = blockIdx.x * 256 + threadIdx.x;  // 0..4095
  int l = tid & 63, s = (tid >> 6) & 3, t = tid >> 8;
  int col = t * 16 + (l & 15);
  int kb = s * 32 + (l >> 4) * 8;
  const float* __restrict__ W = (col < 128) ? Wl : Wr;
  int c = col & 127;
  unsigned p[4];
#pragma unroll
  for (int i = 0; i < 4; ++i) {
    unsigned lo = f2b(W[(size_t)(kb + 2 * i) * 128 + c]);
    unsigned hi = f2b(W[(size_t)(kb + 2 * i + 1) * 128 + c]);
    p[i] = lo | (hi << 16);
  }
  *(uint4*)(Bpack + (size_t)tid * 8) = make_uint4(p[0], p[1], p[2], p[3]);
  if (tid < 256) bcat[tid] = (tid < 128) ? bl[tid] : br[tid - 128];
  if (tid < 8) src_pad[tid] = 0;
  if (tid < 2) red[tid] = 0.0;
  if (tid == 0) *tot = 0;
  for (int i = tid; i < N2; i += 4096) degcur[i] = 0;  // deg + cursor
}

// ---- K1: xl (bf16) | xr (f32, into outz) = x @ (Wl|Wr) + b via bf16 MFMA ----
// Tail: in-degree count folded in (grid-stride over edges).
__global__ __launch_bounds__(256) void k_gemm_mfma(
    const float* __restrict__ x, const ushort* __restrict__ Bpack,
    const float* __restrict__ bcat, ushort* __restrict__ xl,
    float* __restrict__ outz, int n, const int* __restrict__ dst,
    int* __restrict__ deg, int E)
{
  const int lane = threadIdx.x & 63;
  const int w = threadIdx.x >> 6;
  const int row0 = blockIdx.x * 64 + w * 16;
  const int rowA = min(row0 + (lane & 15), n - 1);
  const int kgrp = lane >> 4;

  f32x4 acc[16];
#pragma unroll
  for (int t = 0; t < 16; ++t) acc[t] = (f32x4){0.f, 0.f, 0.f, 0.f};

#pragma unroll
  for (int s = 0; s < 4; ++s) {
    const float4* ap =
        (const float4*)(x + (size_t)rowA * 128 + s * 32 + kgrp * 8);
    float4 a0 = ap[0], a1 = ap[1];
    bf16x8 a;
    a[0] = (short)f2b(a0.x); a[1] = (short)f2b(a0.y);
    a[2] = (short)f2b(a0.z); a[3] = (short)f2b(a0.w);
    a[4] = (short)f2b(a1.x); a[5] = (short)f2b(a1.y);
    a[6] = (short)f2b(a1.z); a[7] = (short)f2b(a1.w);
#pragma unroll
    for (int t = 0; t < 16; ++t) {
      bf16x8 b =
          *(const bf16x8*)(Bpack + (((size_t)t * 4 + s) * 64 + lane) * 8);
      acc[t] = __builtin_amdgcn_mfma_f32_16x16x32_bf16(a, b, acc[t], 0, 0, 0);
    }
  }

  const int colg = lane & 15;
  const int rbase = row0 + (lane >> 4) * 4;
#pragma unroll
  for (int t = 0; t < 16; ++t) {
    const int col = t * 16 + colg;
    const float bia = bcat[col];
    if (col < 128) {
#pragma unroll
      for (int r = 0; r < 4; ++r) {
        const int R = rbase + r;
        if (R < n) xl[(size_t)R * 128 + col] = (ushort)f2b(acc[t][r] + bia);
      }
    } else {
      const int c = col - 128;
#pragma unroll
      for (int r = 0; r < 4; ++r) {
        const int R = rbase + r;
        if (R < n) outz[(size_t)R * 128 + c] = acc[t][r] + bia;
      }
    }
  }

  // folded: in-degree histogram
  for (int e = blockIdx.x * 256 + threadIdx.x; e < E; e += gridDim.x * 256)
    atomicAdd(&deg[dst[e]], 1);
}

// ---- K2: allocate CSR segments: block-local scan + one atomic per block ----
__global__ __launch_bounds__(256) void k_allocscan(
    const int* __restrict__ deg, int* __restrict__ offs, int* __restrict__ tot,
    int n)
{
  __shared__ int s[256];
  __shared__ int base;
  const int b = blockIdx.x, t = threadIdx.x, i = b * 256 + t;
  const int v = (i < n) ? deg[i] : 0;
  s[t] = v;
  __syncthreads();
  for (int o = 1; o < 256; o <<= 1) {
    int u = (t >= o) ? s[t - o] : 0;
    __syncthreads();
    s[t] += u;
    __syncthreads();
  }
  if (t == 255) base = atomicAdd(tot, s[255]);
  __syncthreads();
  if (i < n) offs[i] = base + s[t] - v;
}

// ---- K3: fill dst-CSR: src id + bf16 edge_attr permuted into CSR order ----
__global__ __launch_bounds__(256) void k_fill(
    const int* __restrict__ src, const int* __restrict__ dst,
    const int* __restrict__ offs, int* __restrict__ cursor,
    const float4* __restrict__ ea4, int* __restrict__ csr_src,
    ushort* __restrict__ csr_ea, int E)
{
  int e = blockIdx.x * 256 + threadIdx.x;
  if (e >= E) return;
  int d = dst[e];
  int pos = offs[d] + atomicAdd(&cursor[d], 1);
  csr_src[pos] = src[e];
  float4 r0 = ea4[(size_t)e * 4 + 0], r1 = ea4[(size_t)e * 4 + 1];
  float4 r2 = ea4[(size_t)e * 4 + 2], r3 = ea4[(size_t)e * 4 + 3];
  uint4* o4 = (uint4*)(csr_ea + (size_t)pos * 16);
  o4[0] = make_uint4(f2b(r0.x) | (f2b(r0.y) << 16), f2b(r0.z) | (f2b(r0.w) << 16),
                     f2b(r1.x) | (f2b(r1.y) << 16), f2b(r1.z) | (f2b(r1.w) << 16));
  o4[1] = make_uint4(f2b(r2.x) | (f2b(r2.y) << 16), f2b(r2.z) | (f2b(r2.w) << 16),
                     f2b(r3.x) | (f2b(r3.y) << 16), f2b(r3.z) | (f2b(r3.w) << 16));
}

// ---- K4: fused logits + softmax (no max-sub) + aggregation + z + LN stats --
// One wave per node; lane j owns channels {2j,2j+1}; head = j>>4.
// ea: bf16 in SGPRs (wave-uniform s_load, 1-ahead prefetch; SALU expansion).
// Self-loop emb via linearity: emb(mean ea) = embsum/len.
// No running max (logits O(10), f32 exp safe). xr read from outz (f32).
__global__ __launch_bounds__(256) void k_fused(
    const int* __restrict__ csr_src, const ushort* __restrict__ csr_ea,
    const int* __restrict__ offs, const int* __restrict__ deg,
    const ushort* __restrict__ xl, const float* __restrict__ We,
    const float* __restrict__ att, const float* __restrict__ x,
    const float* __restrict__ bias, float* __restrict__ outz,
    double* __restrict__ red, int N)
{
  const int lane = threadIdx.x & 63;
  const int gw =
      __builtin_amdgcn_readfirstlane(blockIdx.x * 4 + (threadIdx.x >> 6));
  const int nw = gridDim.x * 4;
  const v2f* __restrict__ We2 = (const v2f*)We;
  const v2f* __restrict__ X2 = (const v2f*)x;
  v2f* __restrict__ Z2 = (v2f*)outz;

  v2f we[16];
#pragma unroll
  for (int k = 0; k < 16; ++k) we[k] = We2[k * 64 + lane];
  const v2f a2 = ((const v2f*)att)[lane];
  const v2f b2 = ((const v2f*)bias)[lane];

  float sred = 0.f, s2red = 0.f;

  for (int node = gw; node < N; node += nw) {
    const int beg = offs[node];
    const int len = deg[node];
    const v2f xrv = Z2[(size_t)node * 64 + lane];  // xr row (f32)
    const v2f xvSelf =
        b2f2(*(const ushort2*)(xl + (size_t)node * 128 + 2 * lane));

    float dA = 0.f, dB = 0.f;
    v2f aA = {0.f, 0.f}, aB = {0.f, 0.f};
    v2f embsum = {0.f, 0.f};

    // uniform-ea edge: lo/hi hold 16 bf16 values (8 dwords, SGPRs)
    auto edgeU = [&](v2f xv, uint4 lo, uint4 hi, float& den, v2f& acc) {
      v2f emb = sbl(lo.x) * we[0];
      emb += sbh(lo.x) * we[1];
      emb += sbl(lo.y) * we[2];
      emb += sbh(lo.y) * we[3];
      emb += sbl(lo.z) * we[4];
      emb += sbh(lo.z) * we[5];
      emb += sbl(lo.w) * we[6];
      emb += sbh(lo.w) * we[7];
      emb += sbl(hi.x) * we[8];
      emb += sbh(hi.x) * we[9];
      emb += sbl(hi.y) * we[10];
      emb += sbh(hi.y) * we[11];
      emb += sbl(hi.z) * we[12];
      emb += sbh(hi.z) * we[13];
      emb += sbl(hi.w) * we[14];
      emb += sbh(hi.w) * we[15];
      embsum += emb;
      v2f mm = xv + xrv + emb;
      v2f ml;
      ml.x = fmaxf(mm.x, NEG_SLOPE * mm.x);
      ml.y = fmaxf(mm.y, NEG_SLOPE * mm.y);
      const float part = head_sum16(fmaf(ml.y, a2.y, ml.x * a2.x));
      const float p = __expf(part);
      den += p;
      acc += xv * p;
    };

    const int nB = len >> 1;
    const int nA = len - nB;  // A: [beg, beg+nA), B: [bB, bB+nB)
    const int bB = beg + nA;

    // pipeline registers: ea cur (SGPR), xl row cur, src 1-ahead
    uint4 eAlo = {0, 0, 0, 0}, eAhi = {0, 0, 0, 0};
    uint4 eBlo = {0, 0, 0, 0}, eBhi = {0, 0, 0, 0};
    v2f xvA = {0.f, 0.f}, xvB = {0.f, 0.f};
    int sA1 = 0, sB1 = 0;

    if (len > 0) {
      const uint4* pa = (const uint4*)(csr_ea + (size_t)beg * 16);
      eAlo = pa[0];
      eAhi = pa[1];
      const int sA0 = csr_src[beg];
      xvA = b2f2(*(const ushort2*)(xl + (size_t)sA0 * 128 + 2 * lane));
      sA1 = csr_src[beg + 1];  // padded, safe
    }
    if (nB > 0) {
      const uint4* pb = (const uint4*)(csr_ea + (size_t)bB * 16);
      eBlo = pb[0];
      eBhi = pb[1];
      const int sB0 = csr_src[bB];
      xvB = b2f2(*(const ushort2*)(xl + (size_t)sB0 * 128 + 2 * lane));
      sB1 = csr_src[bB + 1];  // padded, safe
    }

    for (int i = 0; i < nB; ++i) {
      // prefetch for next iteration: ea(i+1), xl(i+1), src(i+2) — all padded
      const uint4* pa = (const uint4*)(csr_ea + (size_t)(beg + i + 1) * 16);
      const uint4* pb = (const uint4*)(csr_ea + (size_t)(bB + i + 1) * 16);
      const uint4 nAlo = pa[0], nAhi = pa[1];
      const uint4 nBlo = pb[0], nBhi = pb[1];
      const v2f xvA1 =
          b2f2(*(const ushort2*)(xl + (size_t)sA1 * 128 + 2 * lane));
      const v2f xvB1 =
          b2f2(*(const ushort2*)(xl + (size_t)sB1 * 128 + 2 * lane));
      const int sA2 = csr_src[beg + i + 2];
      const int sB2 = csr_src[bB + i + 2];
      // process current edges (no loads on the critical path)
      edgeU(xvA, eAlo, eAhi, dA, aA);
      edgeU(xvB, eBlo, eBhi, dB, aB);
      // rotate
      eAlo = nAlo; eAhi = nAhi; eBlo = nBlo; eBhi = nBhi;
      xvA = xvA1; xvB = xvB1;
      sA1 = sA2; sB1 = sB2;
    }
    if (nA > nB) {  // odd tail on stream A (cur regs hold edge beg+nA-1)
      edgeU(xvA, eAlo, eAhi, dA, aA);
    }

    // self loop: emb = embsum/len (linearity of emb in ea); 0 if isolated
    {
      const float inv = (len > 0) ? 1.f / (float)len : 0.f;
      const v2f embS = embsum * inv;
      v2f mm = xvSelf + xrv + embS;
      v2f ml;
      ml.x = fmaxf(mm.x, NEG_SLOPE * mm.x);
      ml.y = fmaxf(mm.y, NEG_SLOPE * mm.y);
      const float part = head_sum16(fmaf(ml.y, a2.y, ml.x * a2.x));
      const float p = __expf(part);
      dA += p;
      aA += xvSelf * p;
    }

    // merge stream B into A (plain adds — no max bookkeeping)
    const float den = dA + dB;
    const float invden = 1.f / den;
    const float o0 = (aA.x + aB.x) * invden;
    const float o1 = (aA.y + aB.y) * invden;

    // z = x + attn + bias (overwrites xr row); LN stats on z
    const v2f xvn = X2[(size_t)node * 64 + lane];
    const float v0 = xvn.x + o0 + b2.x;
    const float v1 = xvn.y + o1 + b2.y;
    Z2[(size_t)node * 64 + lane] = (v2f){v0, v1};
    sred += v0 + v1;
    s2red += v0 * v0 + v1 * v1;
  }

#pragma unroll
  for (int o = 32; o > 0; o >>= 1) {
    sred += __shfl_down(sred, o);
    s2red += __shfl_down(s2red, o);
  }
  __shared__ double ls[4], ls2[4];
  const int w = threadIdx.x >> 6;
  if ((threadIdx.x & 63) == 0) {
    ls[w] = (double)sred;
    ls2[w] = (double)s2red;
  }
  __syncthreads();
  if (threadIdx.x == 0) {
    unsafeAtomicAdd(red, ls[0] + ls[1] + ls[2] + ls[3]);
    unsafeAtomicAdd(red + 1, ls2[0] + ls2[1] + ls2[2] + ls2[3]);
  }
}

// ---- K5: normalize z, scale/shift, relu (in place) ----
__global__ __launch_bounds__(256) void k_final(
    float* __restrict__ z, const double* __restrict__ red,
    const float* __restrict__ lnw, const float* __restrict__ lnb, int M4)
{
  int i = blockIdx.x * 256 + threadIdx.x;
  if (i >= M4) return;
  const double invM = 1.0 / ((double)M4 * 4.0);
  const double mu = red[0] * invM;
  const double var = red[1] * invM - mu * mu;
  const float sc = rsqrtf((float)var + LN_EPS);
  const float muf = (float)mu;
  const float4* W4 = (const float4*)lnw;
  const float4* L4 = (const float4*)lnb;
  float4* Z4 = (float4*)z;
  float4 zv = Z4[i], wv = W4[i & 31], lv = L4[i & 31];
  float4 o;
  o.x = fmaxf((zv.x - muf) * sc * wv.x + lv.x, 0.f);
  o.y = fmaxf((zv.y - muf) * sc * wv.y + lv.y, 0.f);
  o.z = fmaxf((zv.z - muf) * sc * wv.z + lv.z, 0.f);
  o.w = fmaxf((zv.w - muf) * sc * wv.w + lv.w, 0.f);
  Z4[i] = o;
}

extern "C" void kernel_launch(void* const* d_in, const int* in_sizes, int n_in,
                              void* d_out, int out_size, void* d_ws,
                              size_t ws_size, hipStream_t stream)
{
  const float* x = (const float*)d_in[0];
  const int* ei = (const int*)d_in[1];
  const float* edge_attr = (const float*)d_in[2];
  const float* Wl = (const float*)d_in[3];
  const float* bl = (const float*)d_in[4];
  const float* Wr = (const float*)d_in[5];
  const float* br = (const float*)d_in[6];
  const float* We = (const float*)d_in[7];
  const float* att = (const float*)d_in[8];
  const float* bias = (const float*)d_in[9];
  const float* lnw = (const float*)d_in[10];
  const float* lnb = (const float*)d_in[11];
  float* out = (float*)d_out;

  const int N = in_sizes[0] / 128;
  const int E = in_sizes[1] / 2;
  const int M = N * 128;
  const int* srcp = ei;
  const int* dstp = ei + E;
  const int nb = (N + 255) / 256;

  // workspace (~90 MB): xl bf16 | ints | csr_src(+pad) | csr_ea bf16(+pad)
  ushort* xl = (ushort*)d_ws;                      // M ushort
  int* deg = (int*)(xl + (size_t)M);               // N
  int* cursor = deg + N;                           // N
  int* offs = cursor + N;                          // N
  int* tot = offs + N;                             // 1 (+7 pad)
  int* csr_src = tot + 8;                          // E + 8 (padded)
  ushort* csr_ea =
      (ushort*)((((size_t)(csr_src + E + 8)) + 63) & ~(size_t)63);  // E*16+64
  double* red = (double*)(
      (((size_t)(csr_ea + (size_t)E * 16 + 64)) + 127) & ~(size_t)127);
  ushort* Bpack = (ushort*)(red + 8);              // 4096*8 ushort (64 KB)
  float* bcat = (float*)(Bpack + 4096 * 8);        // 256 floats

  k_packB<<<16, 256, 0, stream>>>(Wl, Wr, bl, br, Bpack, bcat, deg, 2 * N,
                                  tot, csr_src + E, red);
  k_gemm_mfma<<<(N + 63) / 64, 256, 0, stream>>>(x, Bpack, bcat, xl, out, N,
                                                 dstp, deg, E);
  k_allocscan<<<nb, 256, 0, stream>>>(deg, offs, tot, N);
  k_fill<<<(E + 255) / 256, 256, 0, stream>>>(srcp, dstp, offs, cursor,
                                              (const float4*)edge_attr,
                                              csr_src, csr_ea, E);
  k_fused<<<2048, 256, 0, stream>>>(csr_src, csr_ea, offs, deg, xl, We, att,
                                    x, bias, out, red, N);
  k_final<<<(M / 4 + 255) / 256, 256, 0, stream>>>(out, red, lnw, lnb, M / 4);
}

// Round 19
// 474.354 us; speedup vs baseline: 1.1566x; 1.0202x over previous
//
#include <hip/hip_runtime.h>
#include <hip/hip_bf16.h>

static constexpr float NEG_SLOPE = 0.2f;
static constexpr float LN_EPS = 1e-5f;

typedef float v2f __attribute__((ext_vector_type(2)));
typedef __attribute__((ext_vector_type(8))) short bf16x8;
typedef __attribute__((ext_vector_type(4))) float f32x4;

// f32 -> bf16 (RNE) as ushort
__device__ __forceinline__ unsigned f2b(float f) {
  unsigned u = __float_as_uint(f);
  return (u + 0x7fffu + ((u >> 16) & 1u)) >> 16;
}
__device__ __forceinline__ v2f b2f2(ushort2 u) {
  v2f r;
  r.x = __uint_as_float((unsigned)u.x << 16);
  r.y = __uint_as_float((unsigned)u.y << 16);
  return r;
}
// bf16-in-dword expansion (SALU when operand is uniform)
__device__ __forceinline__ float sbl(unsigned w) {
  return __uint_as_float(w << 16);
}
__device__ __forceinline__ float sbh(unsigned w) {
  return __uint_as_float(w & 0xFFFF0000u);
}

// ---- 16-lane (head-group) sum via DPP ----
__device__ __forceinline__ float head_sum16(float x) {
  float t;
  t = __int_as_float(__builtin_amdgcn_update_dpp(
      0, __float_as_int(x), 0xB1, 0xF, 0xF, true));  // quad_perm [1,0,3,2]
  x += t;
  t = __int_as_float(__builtin_amdgcn_update_dpp(
      0, __float_as_int(x), 0x4E, 0xF, 0xF, true));  // quad_perm [2,3,0,1]
  x += t;
  t = __int_as_float(__builtin_amdgcn_update_dpp(
      0, __float_as_int(x), 0x124, 0xF, 0xF, true));  // row_ror:4
  x += t;
  t = __int_as_float(__builtin_amdgcn_update_dpp(
      0, __float_as_int(x), 0x128, 0xF, 0xF, true));  // row_ror:8
  x += t;
  return x;
}

// ---- K0: pack Wl|Wr into MFMA B-fragment order (bf16) + bias concat ----
// Also zeroes deg/cursor, the alloc counter, csr_src pad, LN-stat accums.
__global__ __launch_bounds__(256) void k_packB(
    const float* __restrict__ Wl, const float* __restrict__ Wr,
    const float* __restrict__ bl, const float* __restrict__ br,
    ushort* __restrict__ Bpack, float* __restrict__ bcat,
    int* __restrict__ degcur, int N2, int* __restrict__ tot,
    int* __restrict__ src_pad, double* __restrict__ red)
{
  int tid = blockIdx.x * 256 + threadIdx.x;  // 0..4095
  int l = tid & 63, s = (tid >> 6) & 3, t = tid >> 8;
  int col = t * 16 + (l & 15);
  int kb = s * 32 + (l >> 4) * 8;
  const float* __restrict__ W = (col < 128) ? Wl : Wr;
  int c = col & 127;
  unsigned p[4];
#pragma unroll
  for (int i = 0; i < 4; ++i) {
    unsigned lo = f2b(W[(size_t)(kb + 2 * i) * 128 + c]);
    unsigned hi = f2b(W[(size_t)(kb + 2 * i + 1) * 128 + c]);
    p[i] = lo | (hi << 16);
  }
  *(uint4*)(Bpack + (size_t)tid * 8) = make_uint4(p[0], p[1], p[2], p[3]);
  if (tid < 256) bcat[tid] = (tid < 128) ? bl[tid] : br[tid - 128];
  if (tid < 8) src_pad[tid] = 0;
  if (tid < 2) red[tid] = 0.0;
  if (tid == 0) *tot = 0;
  for (int i = tid; i < N2; i += 4096) degcur[i] = 0;  // deg + cursor
}

// ---- K1: xl, xr (both bf16) = x @ (Wl|Wr) + b via bf16 MFMA ----
// Tail: in-degree count folded in (grid-stride over edges).
__global__ __launch_bounds__(256) void k_gemm_mfma(
    const float* __restrict__ x, const ushort* __restrict__ Bpack,
    const float* __restrict__ bcat, ushort* __restrict__ xl,
    ushort* __restrict__ xr, int n, const int* __restrict__ dst,
    int* __restrict__ deg, int E)
{
  const int lane = threadIdx.x & 63;
  const int w = threadIdx.x >> 6;
  const int row0 = blockIdx.x * 64 + w * 16;
  const int rowA = min(row0 + (lane & 15), n - 1);
  const int kgrp = lane >> 4;

  f32x4 acc[16];
#pragma unroll
  for (int t = 0; t < 16; ++t) acc[t] = (f32x4){0.f, 0.f, 0.f, 0.f};

#pragma unroll
  for (int s = 0; s < 4; ++s) {
    const float4* ap =
        (const float4*)(x + (size_t)rowA * 128 + s * 32 + kgrp * 8);
    float4 a0 = ap[0], a1 = ap[1];
    bf16x8 a;
    a[0] = (short)f2b(a0.x); a[1] = (short)f2b(a0.y);
    a[2] = (short)f2b(a0.z); a[3] = (short)f2b(a0.w);
    a[4] = (short)f2b(a1.x); a[5] = (short)f2b(a1.y);
    a[6] = (short)f2b(a1.z); a[7] = (short)f2b(a1.w);
#pragma unroll
    for (int t = 0; t < 16; ++t) {
      bf16x8 b =
          *(const bf16x8*)(Bpack + (((size_t)t * 4 + s) * 64 + lane) * 8);
      acc[t] = __builtin_amdgcn_mfma_f32_16x16x32_bf16(a, b, acc[t], 0, 0, 0);
    }
  }

  const int colg = lane & 15;
  const int rbase = row0 + (lane >> 4) * 4;
#pragma unroll
  for (int t = 0; t < 16; ++t) {
    const int col = t * 16 + colg;
    const float bia = bcat[col];
    ushort* __restrict__ outp = (col < 128) ? xl : xr;
    const int c = col & 127;
#pragma unroll
    for (int r = 0; r < 4; ++r) {
      const int R = rbase + r;
      if (R < n) outp[(size_t)R * 128 + c] = (ushort)f2b(acc[t][r] + bia);
    }
  }

  // folded: in-degree histogram
  for (int e = blockIdx.x * 256 + threadIdx.x; e < E; e += gridDim.x * 256)
    atomicAdd(&deg[dst[e]], 1);
}

// ---- K2: allocate CSR segments: block-local scan + one atomic per block ----
__global__ __launch_bounds__(256) void k_allocscan(
    const int* __restrict__ deg, int* __restrict__ offs, int* __restrict__ tot,
    int n)
{
  __shared__ int s[256];
  __shared__ int base;
  const int b = blockIdx.x, t = threadIdx.x, i = b * 256 + t;
  const int v = (i < n) ? deg[i] : 0;
  s[t] = v;
  __syncthreads();
  for (int o = 1; o < 256; o <<= 1) {
    int u = (t >= o) ? s[t - o] : 0;
    __syncthreads();
    s[t] += u;
    __syncthreads();
  }
  if (t == 255) base = atomicAdd(tot, s[255]);
  __syncthreads();
  if (i < n) offs[i] = base + s[t] - v;
}

// ---- K3: fill dst-CSR: src id + bf16 edge_attr permuted into CSR order ----
__global__ __launch_bounds__(256) void k_fill(
    const int* __restrict__ src, const int* __restrict__ dst,
    const int* __restrict__ offs, int* __restrict__ cursor,
    const float4* __restrict__ ea4, int* __restrict__ csr_src,
    ushort* __restrict__ csr_ea, int E)
{
  int e = blockIdx.x * 256 + threadIdx.x;
  if (e >= E) return;
  int d = dst[e];
  int pos = offs[d] + atomicAdd(&cursor[d], 1);
  csr_src[pos] = src[e];
  float4 r0 = ea4[(size_t)e * 4 + 0], r1 = ea4[(size_t)e * 4 + 1];
  float4 r2 = ea4[(size_t)e * 4 + 2], r3 = ea4[(size_t)e * 4 + 3];
  uint4* o4 = (uint4*)(csr_ea + (size_t)pos * 16);
  o4[0] = make_uint4(f2b(r0.x) | (f2b(r0.y) << 16), f2b(r0.z) | (f2b(r0.w) << 16),
                     f2b(r1.x) | (f2b(r1.y) << 16), f2b(r1.z) | (f2b(r1.w) << 16));
  o4[1] = make_uint4(f2b(r2.x) | (f2b(r2.y) << 16), f2b(r2.z) | (f2b(r2.w) << 16),
                     f2b(r3.x) | (f2b(r3.y) << 16), f2b(r3.z) | (f2b(r3.w) << 16));
}

// ---- K4: fused logits + softmax (no max-sub) + aggregation + z + LN stats --
// One wave per node; lane j owns channels {2j,2j+1}; head = j>>4.
// ea: bf16 in SGPRs (wave-uniform s_load, 1-ahead prefetch; SALU expansion).
// xl, xr both bf16 (R5-validated precision). Self-loop emb via linearity.
// No running max (logits O(10), f32 exp safe).
__global__ __launch_bounds__(256) void k_fused(
    const int* __restrict__ csr_src, const ushort* __restrict__ csr_ea,
    const int* __restrict__ offs, const int* __restrict__ deg,
    const ushort* __restrict__ xl, const ushort* __restrict__ xr,
    const float* __restrict__ We, const float* __restrict__ att,
    const float* __restrict__ x, const float* __restrict__ bias,
    float* __restrict__ outz, double* __restrict__ red, int N)
{
  const int lane = threadIdx.x & 63;
  const int gw =
      __builtin_amdgcn_readfirstlane(blockIdx.x * 4 + (threadIdx.x >> 6));
  const int nw = gridDim.x * 4;
  const v2f* __restrict__ We2 = (const v2f*)We;
  const v2f* __restrict__ X2 = (const v2f*)x;
  v2f* __restrict__ Z2 = (v2f*)outz;

  v2f we[16];
#pragma unroll
  for (int k = 0; k < 16; ++k) we[k] = We2[k * 64 + lane];
  const v2f a2 = ((const v2f*)att)[lane];
  const v2f b2 = ((const v2f*)bias)[lane];

  float sred = 0.f, s2red = 0.f;

  for (int node = gw; node < N; node += nw) {
    const int beg = offs[node];
    const int len = deg[node];
    const v2f xrv = b2f2(*(const ushort2*)(xr + (size_t)node * 128 + 2 * lane));
    const v2f xvSelf =
        b2f2(*(const ushort2*)(xl + (size_t)node * 128 + 2 * lane));

    float dA = 0.f, dB = 0.f;
    v2f aA = {0.f, 0.f}, aB = {0.f, 0.f};
    v2f embsum = {0.f, 0.f};

    // uniform-ea edge: lo/hi hold 16 bf16 values (8 dwords, SGPRs)
    auto edgeU = [&](v2f xv, uint4 lo, uint4 hi, float& den, v2f& acc) {
      v2f emb = sbl(lo.x) * we[0];
      emb += sbh(lo.x) * we[1];
      emb += sbl(lo.y) * we[2];
      emb += sbh(lo.y) * we[3];
      emb += sbl(lo.z) * we[4];
      emb += sbh(lo.z) * we[5];
      emb += sbl(lo.w) * we[6];
      emb += sbh(lo.w) * we[7];
      emb += sbl(hi.x) * we[8];
      emb += sbh(hi.x) * we[9];
      emb += sbl(hi.y) * we[10];
      emb += sbh(hi.y) * we[11];
      emb += sbl(hi.z) * we[12];
      emb += sbh(hi.z) * we[13];
      emb += sbl(hi.w) * we[14];
      emb += sbh(hi.w) * we[15];
      embsum += emb;
      v2f mm = xv + xrv + emb;
      v2f ml;
      ml.x = fmaxf(mm.x, NEG_SLOPE * mm.x);
      ml.y = fmaxf(mm.y, NEG_SLOPE * mm.y);
      const float part = head_sum16(fmaf(ml.y, a2.y, ml.x * a2.x));
      const float p = __expf(part);
      den += p;
      acc += xv * p;
    };

    const int nB = len >> 1;
    const int nA = len - nB;  // A: [beg, beg+nA), B: [bB, bB+nB)
    const int bB = beg + nA;

    // pipeline registers: ea cur (SGPR), xl row cur, src 1-ahead
    uint4 eAlo = {0, 0, 0, 0}, eAhi = {0, 0, 0, 0};
    uint4 eBlo = {0, 0, 0, 0}, eBhi = {0, 0, 0, 0};
    v2f xvA = {0.f, 0.f}, xvB = {0.f, 0.f};
    int sA1 = 0, sB1 = 0;

    if (len > 0) {
      const uint4* pa = (const uint4*)(csr_ea + (size_t)beg * 16);
      eAlo = pa[0];
      eAhi = pa[1];
      const int sA0 = csr_src[beg];
      xvA = b2f2(*(const ushort2*)(xl + (size_t)sA0 * 128 + 2 * lane));
      sA1 = csr_src[beg + 1];  // padded, safe
    }
    if (nB > 0) {
      const uint4* pb = (const uint4*)(csr_ea + (size_t)bB * 16);
      eBlo = pb[0];
      eBhi = pb[1];
      const int sB0 = csr_src[bB];
      xvB = b2f2(*(const ushort2*)(xl + (size_t)sB0 * 128 + 2 * lane));
      sB1 = csr_src[bB + 1];  // padded, safe
    }

    for (int i = 0; i < nB; ++i) {
      // prefetch for next iteration: ea(i+1), xl(i+1), src(i+2) — all padded
      const uint4* pa = (const uint4*)(csr_ea + (size_t)(beg + i + 1) * 16);
      const uint4* pb = (const uint4*)(csr_ea + (size_t)(bB + i + 1) * 16);
      const uint4 nAlo = pa[0], nAhi = pa[1];
      const uint4 nBlo = pb[0], nBhi = pb[1];
      const v2f xvA1 =
          b2f2(*(const ushort2*)(xl + (size_t)sA1 * 128 + 2 * lane));
      const v2f xvB1 =
          b2f2(*(const ushort2*)(xl + (size_t)sB1 * 128 + 2 * lane));
      const int sA2 = csr_src[beg + i + 2];
      const int sB2 = csr_src[bB + i + 2];
      // process current edges (no loads on the critical path)
      edgeU(xvA, eAlo, eAhi, dA, aA);
      edgeU(xvB, eBlo, eBhi, dB, aB);
      // rotate
      eAlo = nAlo; eAhi = nAhi; eBlo = nBlo; eBhi = nBhi;
      xvA = xvA1; xvB = xvB1;
      sA1 = sA2; sB1 = sB2;
    }
    if (nA > nB) {  // odd tail on stream A (cur regs hold edge beg+nA-1)
      edgeU(xvA, eAlo, eAhi, dA, aA);
    }

    // self loop: emb = embsum/len (linearity of emb in ea); 0 if isolated
    {
      const float inv = (len > 0) ? 1.f / (float)len : 0.f;
      const v2f embS = embsum * inv;
      v2f mm = xvSelf + xrv + embS;
      v2f ml;
      ml.x = fmaxf(mm.x, NEG_SLOPE * mm.x);
      ml.y = fmaxf(mm.y, NEG_SLOPE * mm.y);
      const float part = head_sum16(fmaf(ml.y, a2.y, ml.x * a2.x));
      const float p = __expf(part);
      dA += p;
      aA += xvSelf * p;
    }

    // merge stream B into A (plain adds — no max bookkeeping)
    const float den = dA + dB;
    const float invden = 1.f / den;
    const float o0 = (aA.x + aB.x) * invden;
    const float o1 = (aA.y + aB.y) * invden;

    // z = x + attn + bias; LN stats on z
    const v2f xvn = X2[(size_t)node * 64 + lane];
    const float v0 = xvn.x + o0 + b2.x;
    const float v1 = xvn.y + o1 + b2.y;
    Z2[(size_t)node * 64 + lane] = (v2f){v0, v1};
    sred += v0 + v1;
    s2red += v0 * v0 + v1 * v1;
  }

#pragma unroll
  for (int o = 32; o > 0; o >>= 1) {
    sred += __shfl_down(sred, o);
    s2red += __shfl_down(s2red, o);
  }
  __shared__ double ls[4], ls2[4];
  const int w = threadIdx.x >> 6;
  if ((threadIdx.x & 63) == 0) {
    ls[w] = (double)sred;
    ls2[w] = (double)s2red;
  }
  __syncthreads();
  if (threadIdx.x == 0) {
    unsafeAtomicAdd(red, ls[0] + ls[1] + ls[2] + ls[3]);
    unsafeAtomicAdd(red + 1, ls2[0] + ls2[1] + ls2[2] + ls2[3]);
  }
}

// ---- K5: normalize z, scale/shift, relu (in place) ----
__global__ __launch_bounds__(256) void k_final(
    float* __restrict__ z, const double* __restrict__ red,
    const float* __restrict__ lnw, const float* __restrict__ lnb, int M4)
{
  int i = blockIdx.x * 256 + threadIdx.x;
  if (i >= M4) return;
  const double invM = 1.0 / ((double)M4 * 4.0);
  const double mu = red[0] * invM;
  const double var = red[1] * invM - mu * mu;
  const float sc = rsqrtf((float)var + LN_EPS);
  const float muf = (float)mu;
  const float4* W4 = (const float4*)lnw;
  const float4* L4 = (const float4*)lnb;
  float4* Z4 = (float4*)z;
  float4 zv = Z4[i], wv = W4[i & 31], lv = L4[i & 31];
  float4 o;
  o.x = fmaxf((zv.x - muf) * sc * wv.x + lv.x, 0.f);
  o.y = fmaxf((zv.y - muf) * sc * wv.y + lv.y, 0.f);
  o.z = fmaxf((zv.z - muf) * sc * wv.z + lv.z, 0.f);
  o.w = fmaxf((zv.w - muf) * sc * wv.w + lv.w, 0.f);
  Z4[i] = o;
}

extern "C" void kernel_launch(void* const* d_in, const int* in_sizes, int n_in,
                              void* d_out, int out_size, void* d_ws,
                              size_t ws_size, hipStream_t stream)
{
  const float* x = (const float*)d_in[0];
  const int* ei = (const int*)d_in[1];
  const float* edge_attr = (const float*)d_in[2];
  const float* Wl = (const float*)d_in[3];
  const float* bl = (const float*)d_in[4];
  const float* Wr = (const float*)d_in[5];
  const float* br = (const float*)d_in[6];
  const float* We = (const float*)d_in[7];
  const float* att = (const float*)d_in[8];
  const float* bias = (const float*)d_in[9];
  const float* lnw = (const float*)d_in[10];
  const float* lnb = (const float*)d_in[11];
  float* out = (float*)d_out;

  const int N = in_sizes[0] / 128;
  const int E = in_sizes[1] / 2;
  const int M = N * 128;
  const int* srcp = ei;
  const int* dstp = ei + E;
  const int nb = (N + 255) / 256;

  // workspace (~116 MB): xl bf16 | xr bf16 | ints | csr_src | csr_ea bf16
  ushort* xl = (ushort*)d_ws;                      // M ushort
  ushort* xr = xl + (size_t)M;                     // M ushort
  int* deg = (int*)(xr + (size_t)M);               // N
  int* cursor = deg + N;                           // N
  int* offs = cursor + N;                          // N
  int* tot = offs + N;                             // 1 (+7 pad)
  int* csr_src = tot + 8;                          // E + 8 (padded)
  ushort* csr_ea =
      (ushort*)((((size_t)(csr_src + E + 8)) + 63) & ~(size_t)63);  // E*16+64
  double* red = (double*)(
      (((size_t)(csr_ea + (size_t)E * 16 + 64)) + 127) & ~(size_t)127);
  ushort* Bpack = (ushort*)(red + 8);              // 4096*8 ushort (64 KB)
  float* bcat = (float*)(Bpack + 4096 * 8);        // 256 floats

  k_packB<<<16, 256, 0, stream>>>(Wl, Wr, bl, br, Bpack, bcat, deg, 2 * N,
                                  tot, csr_src + E, red);
  k_gemm_mfma<<<(N + 63) / 64, 256, 0, stream>>>(x, Bpack, bcat, xl, xr, N,
                                                 dstp, deg, E);
  k_allocscan<<<nb, 256, 0, stream>>>(deg, offs, tot, N);
  k_fill<<<(E + 255) / 256, 256, 0, stream>>>(srcp, dstp, offs, cursor,
                                              (const float4*)edge_attr,
                                              csr_src, csr_ea, E);
  k_fused<<<2048, 256, 0, stream>>>(csr_src, csr_ea, offs, deg, xl, xr, We,
                                    att, x, bias, out, red, N);
  k_final<<<(M / 4 + 255) / 256, 256, 0, stream>>>(out, red, lnw, lnb, M / 4);
}